// Round 4
// baseline (2177.532 us; speedup 1.0000x reference)
//
#include <hip/hip_runtime.h>

#define B_   64
#define C_   64
#define O_   64
#define H_   32
#define W_   32
#define L_   1024
#define CKK_ 576

#define NTHREADS  512
#define OT_       2                        // o's per block (was 4: spilled)
#define ROWSTRIDE 36                       // 32 data floats + 4 permanent-zero pad
#define BUFFLOATS (64 * 4 * ROWSTRIDE)     // 9216 floats per buffer
#define LDSFLOATS (4 + 2 * BUFFLOATS)      // 4-float zero guard + 2 buffers

// 512 thr, min 4 waves/EU (=16 waves/CU = 2 blocks/CU) -> VGPR cap 128, no spill
__global__ __launch_bounds__(NTHREADS, 4)
void lcl_kernel(const float* __restrict__ x,
                const float* __restrict__ w,
                const float* __restrict__ bias,
                float* __restrict__ out)
{
    __shared__ float lds[LDSFLOATS];

    const int tid  = threadIdx.x;
    const int lane = tid & 63;
    const int wave = tid >> 6;          // 0..7
    const int ly   = lane >> 5;         // 0..1  (row within l-tile)
    const int lx   = lane & 31;         // col

    const int bid = blockIdx.x;
    const int lt  = bid & 15;           // l-tile index (XCD = bid%8 = lt%8 -> x L2 locality)
    const int oti = bid >> 4;           // o-tile index 0..31
    const int y0  = lt * 2;
    const int lg  = lt * 64 + lane;     // global pixel l
    const int o0  = oti * OT_;
    const int b0  = wave * 8;

    // ---- zero all of LDS once (pads/guard/invalid rows stay zero forever) ----
    for (int i = tid; i < LDSFLOATS; i += NTHREADS) lds[i] = 0.0f;

    // ---- staging assignment: thread -> ((b_s, r_s), half-row h) ----
    const int p   = tid >> 1;           // 0..255
    const int h   = tid & 1;
    const int b_s = p >> 2;
    const int r_s = p & 3;              // local row 0..3 <-> global row y0-1+r_s
    const int gy  = y0 - 1 + r_s;
    const bool valid = (unsigned)gy < (unsigned)H_;
    const float* xrow = x + ((size_t)(b_s * C_) * H_ + gy) * W_ + h * 16;  // + c*H_*W_
    float* sdst0 = lds + 4 + p * ROWSTRIDE + h * 16;                       // + buf*BUFFLOATS

    float4 sreg[4];
    float  wA[OT_ * 9], wB[OT_ * 9];
    float  acc[8][OT_];
#pragma unroll
    for (int b = 0; b < 8; ++b)
#pragma unroll
        for (int o = 0; o < OT_; ++o) acc[b][o] = 0.0f;

    // per-thread LDS read base: guard(4) + b0 rows + ly row + (lx-1) left tap
    const float* rbase0 = lds + 4 + b0 * (4 * ROWSTRIDE) + ly * ROWSTRIDE + lx - 1;

    const float* wbase = w + (size_t)(o0 * CKK_) * L_ + lg;

#define STAGE_LOAD(c_) do {                                                   \
    if (valid) {                                                              \
        const float4* xp = (const float4*)(xrow + (size_t)(c_) * (H_ * W_));  \
        sreg[0] = xp[0]; sreg[1] = xp[1]; sreg[2] = xp[2]; sreg[3] = xp[3];   \
    } } while (0)

#define STAGE_WRITE(buf_) do {                                                \
    if (valid) {                                                              \
        float4* d = (float4*)(sdst0 + (buf_) * BUFFLOATS);                    \
        d[0] = sreg[0]; d[1] = sreg[1]; d[2] = sreg[2]; d[3] = sreg[3];       \
    } } while (0)

#define WLOAD(arr, c_) do {                                                   \
    _Pragma("unroll")                                                         \
    for (int ot = 0; ot < OT_; ++ot)                                          \
        _Pragma("unroll")                                                     \
        for (int ij = 0; ij < 9; ++ij)                                        \
            arr[ot * 9 + ij] =                                                \
                wbase[((size_t)ot * CKK_ + (c_) * 9 + ij) * L_];              \
    } while (0)

#define COMPUTE(arr, buf_) do {                                               \
    const float* rb = rbase0 + (buf_) * BUFFLOATS;                            \
    _Pragma("unroll")                                                         \
    for (int i = 0; i < 3; ++i) {                                             \
        _Pragma("unroll")                                                     \
        for (int b = 0; b < 8; ++b) {                                         \
            const float* row = rb + b * (4 * ROWSTRIDE) + i * ROWSTRIDE;      \
            float u0 = row[0], u1 = row[1], u2 = row[2];                      \
            _Pragma("unroll")                                                 \
            for (int ot = 0; ot < OT_; ++ot) {                                \
                acc[b][ot] += arr[ot * 9 + i * 3 + 0] * u0;                   \
                acc[b][ot] += arr[ot * 9 + i * 3 + 1] * u1;                   \
                acc[b][ot] += arr[ot * 9 + i * 3 + 2] * u2;                   \
            }                                                                 \
        }                                                                     \
    } } while (0)

    // ---- prologue ----
    STAGE_LOAD(0);
    WLOAD(wA, 0);
    __syncthreads();          // zero-init complete
    STAGE_WRITE(0);
    __syncthreads();          // c=0 tile visible

    // ---- main loop: double-buffered LDS, W ping-ponged one c ahead ----
    for (int cc = 0; cc < 64; cc += 2) {
        // even c = cc: data in buf0, weights wA
        STAGE_LOAD(cc + 1);
        WLOAD(wB, cc + 1);
        COMPUTE(wA, 0);
        STAGE_WRITE(1);
        __syncthreads();

        // odd c = cc+1: buf1, wB
        const bool more = (cc + 2 < 64);
        if (more) { STAGE_LOAD(cc + 2); WLOAD(wA, cc + 2); }
        COMPUTE(wB, 1);
        if (more) STAGE_WRITE(0);
        __syncthreads();
    }

    // ---- epilogue: out = acc + bias ----
#pragma unroll
    for (int ot = 0; ot < OT_; ++ot) {
        const float bv = bias[(o0 + ot) * L_ + lg];
#pragma unroll
        for (int b = 0; b < 8; ++b) {
            out[((size_t)((b0 + b) * O_) + o0 + ot) * L_ + lg] = acc[b][ot] + bv;
        }
    }

#undef STAGE_LOAD
#undef STAGE_WRITE
#undef WLOAD
#undef COMPUTE
}

extern "C" void kernel_launch(void* const* d_in, const int* in_sizes, int n_in,
                              void* d_out, int out_size, void* d_ws, size_t ws_size,
                              hipStream_t stream) {
    const float* x    = (const float*)d_in[0];
    const float* wght = (const float*)d_in[1];
    const float* bias = (const float*)d_in[2];
    float* out        = (float*)d_out;

    dim3 grid(512), block(NTHREADS);
    hipLaunchKernelGGL(lcl_kernel, grid, block, 0, stream, x, wght, bias, out);
}

// Round 5
// 558.338 us; speedup vs baseline: 3.9000x; 3.9000x over previous
//
#include <hip/hip_runtime.h>

#define B_   64
#define C_   64
#define O_   64
#define H_   32
#define W_   32
#define L_   1024
#define CKK_ 576

#define NTHREADS  512
#define OT_       2                        // o's per block
#define ROWSTRIDE 36                       // 32 data floats + 4 permanent-zero pad
#define BUFFLOATS (64 * 4 * ROWSTRIDE)     // 9216 floats per buffer
#define LDSFLOATS (4 + 2 * BUFFLOATS)      // 4-float zero guard + 2 buffers

// NOTE (measured R3/R4): arg2 acts as min-BLOCKS/CU on this toolchain:
// (512,2) -> 128 VGPR cap, (512,4) -> 64 VGPR cap. Demand here ~75 -> no spill at 128.
__global__ __launch_bounds__(NTHREADS, 2)
void lcl_kernel(const float* __restrict__ x,
                const float* __restrict__ w,
                const float* __restrict__ bias,
                float* __restrict__ out)
{
    __shared__ float lds[LDSFLOATS];

    const int tid  = threadIdx.x;
    const int lane = tid & 63;
    const int wave = tid >> 6;          // 0..7
    const int ly   = lane >> 5;         // 0..1  (row within l-tile)
    const int lx   = lane & 31;         // col

    const int bid = blockIdx.x;
    const int lt  = bid & 15;           // l-tile index (XCD = bid%8 -> x L2 locality)
    const int oti = bid >> 4;           // o-tile index 0..31
    const int y0  = lt * 2;
    const int lg  = lt * 64 + lane;     // global pixel l
    const int o0  = oti * OT_;
    const int b0  = wave * 8;

    // ---- zero all of LDS once (pads/guard/invalid rows stay zero forever) ----
    for (int i = tid; i < LDSFLOATS; i += NTHREADS) lds[i] = 0.0f;

    // ---- staging assignment: thread -> ((b_s, r_s), half-row h) ----
    const int p   = tid >> 1;           // 0..255
    const int h   = tid & 1;
    const int b_s = p >> 2;
    const int r_s = p & 3;              // local row 0..3 <-> global row y0-1+r_s
    const int gy  = y0 - 1 + r_s;
    const bool valid = (unsigned)gy < (unsigned)H_;
    const float* xrow = x + ((size_t)(b_s * C_) * H_ + gy) * W_ + h * 16;  // + c*H_*W_
    float* sdst0 = lds + 4 + p * ROWSTRIDE + h * 16;                       // + buf*BUFFLOATS

    float4 sreg[4];
    float  wA[OT_ * 9];
    float  acc[8][OT_];
#pragma unroll
    for (int b = 0; b < 8; ++b)
#pragma unroll
        for (int o = 0; o < OT_; ++o) acc[b][o] = 0.0f;

    // per-thread LDS read base: guard(4) + b0 rows + ly row + (lx-1) left tap
    const float* rbase0 = lds + 4 + b0 * (4 * ROWSTRIDE) + ly * ROWSTRIDE + lx - 1;

    const float* wbase = w + (size_t)(o0 * CKK_) * L_ + lg;

#define STAGE_LOAD(c_) do {                                                   \
    if (valid) {                                                              \
        const float4* xp = (const float4*)(xrow + (size_t)(c_) * (H_ * W_));  \
        sreg[0] = xp[0]; sreg[1] = xp[1]; sreg[2] = xp[2]; sreg[3] = xp[3];   \
    } } while (0)

#define STAGE_WRITE(buf_) do {                                                \
    if (valid) {                                                              \
        float4* d = (float4*)(sdst0 + (buf_) * BUFFLOATS);                    \
        d[0] = sreg[0]; d[1] = sreg[1]; d[2] = sreg[2]; d[3] = sreg[3];       \
    } } while (0)

#define WLOAD(c_) do {                                                        \
    _Pragma("unroll")                                                         \
    for (int ot = 0; ot < OT_; ++ot)                                          \
        _Pragma("unroll")                                                     \
        for (int ij = 0; ij < 9; ++ij)                                        \
            wA[ot * 9 + ij] =                                                 \
                wbase[((size_t)ot * CKK_ + (c_) * 9 + ij) * L_];              \
    } while (0)

#define COMPUTE(buf_) do {                                                    \
    const float* rb = rbase0 + (buf_) * BUFFLOATS;                            \
    _Pragma("unroll")                                                         \
    for (int i = 0; i < 3; ++i) {                                             \
        _Pragma("unroll")                                                     \
        for (int b = 0; b < 8; ++b) {                                         \
            const float* row = rb + b * (4 * ROWSTRIDE) + i * ROWSTRIDE;      \
            float u0 = row[0], u1 = row[1], u2 = row[2];                      \
            _Pragma("unroll")                                                 \
            for (int ot = 0; ot < OT_; ++ot) {                                \
                acc[b][ot] += wA[ot * 9 + i * 3 + 0] * u0;                    \
                acc[b][ot] += wA[ot * 9 + i * 3 + 1] * u1;                    \
                acc[b][ot] += wA[ot * 9 + i * 3 + 2] * u2;                    \
            }                                                                 \
        }                                                                     \
    } } while (0)

    // ---- prologue ----
    STAGE_LOAD(0);
    __syncthreads();          // zero-init complete
    STAGE_WRITE(0);
    __syncthreads();          // c=0 tile visible

    // ---- main loop: double-buffered x in LDS; W loaded per-c (TLP hides latency) ----
    for (int cc = 0; cc < 64; cc += 2) {
        // even c = cc: data in buf0
        STAGE_LOAD(cc + 1);
        WLOAD(cc);
        COMPUTE(0);
        STAGE_WRITE(1);
        __syncthreads();

        // odd c = cc+1: buf1
        const bool more = (cc + 2 < 64);
        if (more) STAGE_LOAD(cc + 2);
        WLOAD(cc + 1);
        COMPUTE(1);
        if (more) STAGE_WRITE(0);
        __syncthreads();
    }

    // ---- epilogue: out = acc + bias ----
#pragma unroll
    for (int ot = 0; ot < OT_; ++ot) {
        const float bv = bias[(o0 + ot) * L_ + lg];
#pragma unroll
        for (int b = 0; b < 8; ++b) {
            out[((size_t)((b0 + b) * O_) + o0 + ot) * L_ + lg] = acc[b][ot] + bv;
        }
    }

#undef STAGE_LOAD
#undef STAGE_WRITE
#undef WLOAD
#undef COMPUTE
}

extern "C" void kernel_launch(void* const* d_in, const int* in_sizes, int n_in,
                              void* d_out, int out_size, void* d_ws, size_t ws_size,
                              hipStream_t stream) {
    const float* x    = (const float*)d_in[0];
    const float* wght = (const float*)d_in[1];
    const float* bias = (const float*)d_in[2];
    float* out        = (float*)d_out;

    dim3 grid(512), block(NTHREADS);
    hipLaunchKernelGGL(lcl_kernel, grid, block, 0, stream, x, wght, bias, out);
}

// Round 6
// 520.694 us; speedup vs baseline: 4.1820x; 1.0723x over previous
//
#include <hip/hip_runtime.h>

#define B_   64
#define C_   64
#define O_   64
#define H_   32
#define W_   32
#define L_   1024
#define CKK_ 576

#define NTHREADS   512
#define OT_        2                        // o's per block
#define ROWSTRIDE  36                       // 32 data floats + 4 permanent-zero pad
#define WAVEFLOATS (8 * 4 * ROWSTRIDE)      // per-wave slab: 8 b x 4 rows x 36 = 1152
#define BUFFLOATS  (8 * WAVEFLOATS)         // 8 waves = 9216 floats per buffer
#define LDSFLOATS  (4 + 2 * BUFFLOATS)      // 4-float zero guard + 2 buffers

// (512,2) measured on this toolchain (R3/R4): VGPR cap 128. Demand ~100 -> no spill.
__global__ __launch_bounds__(NTHREADS, 2)
void lcl_kernel(const float* __restrict__ x,
                const float* __restrict__ w,
                const float* __restrict__ bias,
                float* __restrict__ out)
{
    __shared__ float lds[LDSFLOATS];

    const int tid  = threadIdx.x;
    const int lane = tid & 63;
    const int wave = tid >> 6;          // 0..7
    const int ly   = lane >> 5;         // 0..1  (pixel row within l-tile)
    const int lx   = lane & 31;         // pixel col

    const int bid = blockIdx.x;
    const int lt  = bid & 15;           // l-tile (XCD = bid%8 -> x L2 locality)
    const int oti = bid >> 4;           // o-tile 0..31
    const int y0  = lt * 2;
    const int lg  = lt * 64 + lane;     // global pixel l
    const int o0  = oti * OT_;
    const int b0  = wave * 8;           // wave-private batch range

    // ---- zero all of LDS once: guard + pad cols + halo rows stay zero forever ----
    for (int i = tid; i < LDSFLOATS; i += NTHREADS) lds[i] = 0.0f;

    // ---- wave-private staging: lane -> (bb, r_s, half h); 16 floats per lane ----
    const int bb_s = lane >> 3;         // 0..7 (batch within wave)
    const int r_s  = (lane >> 1) & 3;   // local row 0..3 <-> global row y0-1+r_s
    const int h    = lane & 1;
    const int gy   = y0 - 1 + r_s;
    const bool valid = (unsigned)gy < (unsigned)H_;   // block-constant rows: stay zero if invalid
    const float* xrow = x + ((size_t)((b0 + bb_s) * C_) * H_ + gy) * W_ + h * 16; // + c*H*W
    float* sdst0 = lds + 4 + wave * WAVEFLOATS
                       + (bb_s * 4 + r_s) * ROWSTRIDE + h * 16;                   // + buf*BUFFLOATS

    float4 sreg[4];
    float  wA[OT_ * 9], wB[OT_ * 9];
    float  acc[8][OT_];
#pragma unroll
    for (int b = 0; b < 8; ++b)
#pragma unroll
        for (int o = 0; o < OT_; ++o) acc[b][o] = 0.0f;

    // per-thread LDS read base: guard(4) + own wave slab + ly row + left tap.
    // Underflow (lx==0,ly==0,bb==0) lands in guard or neighbor's zero pad col.
    const float* rbase0 = lds + 4 + wave * WAVEFLOATS + ly * ROWSTRIDE + lx - 1;

    const float* wbase = w + (size_t)(o0 * CKK_) * L_ + lg;

#define STAGE_LOAD(c_) do {                                                   \
    if (valid) {                                                              \
        const float4* xp = (const float4*)(xrow + (size_t)(c_) * (H_ * W_));  \
        sreg[0] = xp[0]; sreg[1] = xp[1]; sreg[2] = xp[2]; sreg[3] = xp[3];   \
    } } while (0)

#define STAGE_WRITE(buf_) do {                                                \
    if (valid) {                                                              \
        float4* d = (float4*)(sdst0 + (buf_) * BUFFLOATS);                    \
        d[0] = sreg[0]; d[1] = sreg[1]; d[2] = sreg[2]; d[3] = sreg[3];       \
    } } while (0)

#define WLOAD(arr, c_) do {                                                   \
    _Pragma("unroll")                                                         \
    for (int ot = 0; ot < OT_; ++ot)                                          \
        _Pragma("unroll")                                                     \
        for (int ij = 0; ij < 9; ++ij)                                       \
            arr[ot * 9 + ij] =                                                \
                wbase[((size_t)ot * CKK_ + (c_) * 9 + ij) * L_];              \
    } while (0)

#define COMPUTE(arr, buf_) do {                                               \
    const float* rb = rbase0 + (buf_) * BUFFLOATS;                            \
    _Pragma("unroll")                                                         \
    for (int i = 0; i < 3; ++i) {                                             \
        _Pragma("unroll")                                                     \
        for (int b = 0; b < 8; ++b) {                                         \
            const float* row = rb + b * (4 * ROWSTRIDE) + i * ROWSTRIDE;      \
            float u0 = row[0], u1 = row[1], u2 = row[2];                      \
            _Pragma("unroll")                                                 \
            for (int ot = 0; ot < OT_; ++ot) {                                \
                acc[b][ot] += arr[ot * 9 + i * 3 + 0] * u0;                   \
                acc[b][ot] += arr[ot * 9 + i * 3 + 1] * u1;                   \
                acc[b][ot] += arr[ot * 9 + i * 3 + 2] * u2;                   \
            }                                                                 \
        }                                                                     \
    } } while (0)

    // ---- prologue ----
    STAGE_LOAD(0);
    WLOAD(wA, 0);
    __syncthreads();          // only barrier: LDS zero-init visible to all waves
    STAGE_WRITE(0);

    // ---- barrier-free main loop: wave-private dbuf x + W reg ping-pong ----
    for (int cc = 0; cc < 62; cc += 2) {
        STAGE_LOAD(cc + 1);   // x for c=cc+1 -> sreg (in flight under compute)
        WLOAD(wB, cc + 1);    // W for c=cc+1 (in flight under compute)
        COMPUTE(wA, 0);       // consume buf0 = x(cc), wA = W(cc)
        STAGE_WRITE(1);       // land x(cc+1)
        STAGE_LOAD(cc + 2);
        WLOAD(wA, cc + 2);
        COMPUTE(wB, 1);       // consume buf1 = x(cc+1), wB = W(cc+1)
        STAGE_WRITE(0);       // land x(cc+2)
    }
    // tail cc=62: buf0 = x(62), wA = W(62)
    STAGE_LOAD(63);
    WLOAD(wB, 63);
    COMPUTE(wA, 0);
    STAGE_WRITE(1);
    COMPUTE(wB, 1);

    // ---- epilogue: out = acc + bias ----
#pragma unroll
    for (int ot = 0; ot < OT_; ++ot) {
        const float bv = bias[(o0 + ot) * L_ + lg];
#pragma unroll
        for (int b = 0; b < 8; ++b) {
            out[((size_t)((b0 + b) * O_) + o0 + ot) * L_ + lg] = acc[b][ot] + bv;
        }
    }

#undef STAGE_LOAD
#undef STAGE_WRITE
#undef WLOAD
#undef COMPUTE
}

extern "C" void kernel_launch(void* const* d_in, const int* in_sizes, int n_in,
                              void* d_out, int out_size, void* d_ws, size_t ws_size,
                              hipStream_t stream) {
    const float* x    = (const float*)d_in[0];
    const float* wght = (const float*)d_in[1];
    const float* bias = (const float*)d_in[2];
    float* out        = (float*)d_out;

    dim3 grid(512), block(NTHREADS);
    hipLaunchKernelGGL(lcl_kernel, grid, block, 0, stream, x, wght, bias, out);
}